// Round 7
// baseline (2217.538 us; speedup 1.0000x reference)
//
#include <hip/hip_runtime.h>
#include <stdint.h>

#define THREADS 256
#define ITEMS 16
#define CHUNK (THREADS * ITEMS)
#define COLMASK 0xFFFFFu

// ---------------- threefry2x32, JAX-compatible (20 rounds) ----------------
__host__ __device__ static inline void tf2x32(uint32_t k0, uint32_t k1,
                                              uint32_t x0, uint32_t x1,
                                              uint32_t* o0, uint32_t* o1) {
  uint32_t ks[3] = {k0, k1, k0 ^ k1 ^ 0x1BD11BDAu};
  x0 += ks[0]; x1 += ks[1];
  const uint32_t RA[4] = {13u, 15u, 26u, 6u};
  const uint32_t RB[4] = {17u, 29u, 16u, 24u};
#pragma unroll
  for (int g = 0; g < 5; ++g) {
    const uint32_t* R = (g & 1) ? RB : RA;
#pragma unroll
    for (int j = 0; j < 4; ++j) {
      x0 += x1;
      x1 = (x1 << R[j]) | (x1 >> (32u - R[j]));
      x1 ^= x0;
    }
    x0 += ks[(g + 1) % 3];
    x1 += ks[(g + 2) % 3] + (uint32_t)(g + 1);
  }
  *o0 = x0; *o1 = x1;
}

__device__ static inline uint32_t rbits32(uint32_t ka, uint32_t kb, uint32_t i) {
  uint32_t o0, o1;
  tf2x32(ka, kb, 0u, i, &o0, &o1);
  return o0 ^ o1;
}

// ---------------- block exclusive scan (all threads must call) ----------------
__device__ static inline uint32_t block_scan_excl(uint32_t v, uint32_t* lds) {
  int t = threadIdx.x;
  lds[t] = v;
  __syncthreads();
#pragma unroll
  for (int d = 1; d < THREADS; d <<= 1) {
    uint32_t add = (t >= d) ? lds[t - d] : 0u;
    __syncthreads();
    lds[t] += add;
    __syncthreads();
  }
  return lds[t] - v;
}

// ---------------- hierarchical scan helpers ----------------
__global__ void k_sums_u32(const uint32_t* __restrict__ d, int n, uint32_t* __restrict__ bsums) {
  __shared__ uint32_t lds[THREADS];
  int b = blockIdx.x, t = threadIdx.x;
  int base = b * CHUNK + t * ITEMS;
  uint32_t s = 0;
#pragma unroll
  for (int j = 0; j < ITEMS; ++j) { int i = base + j; if (i < n) s += d[i]; }
  lds[t] = s; __syncthreads();
  for (int d2 = THREADS / 2; d2 > 0; d2 >>= 1) { if (t < d2) lds[t] += lds[t + d2]; __syncthreads(); }
  if (t == 0) bsums[b] = lds[0];
}

__global__ void k_scan_single(uint32_t* __restrict__ d, int n, uint32_t* __restrict__ total_out) {
  __shared__ uint32_t lds[THREADS];
  int t = threadIdx.x;
  int K = (n + THREADS - 1) / THREADS;
  int s0 = t * K, s1 = (s0 + K < n) ? (s0 + K) : n;
  uint32_t s = 0;
  for (int j = s0; j < s1; ++j) s += d[j];
  lds[t] = s; __syncthreads();
#pragma unroll
  for (int dd = 1; dd < THREADS; dd <<= 1) {
    uint32_t a = (t >= dd) ? lds[t - dd] : 0u;
    __syncthreads();
    lds[t] += a;
    __syncthreads();
  }
  uint32_t incl = lds[t];
  if (total_out && t == THREADS - 1) *total_out = incl;
  uint32_t run = incl - s;
  for (int j = s0; j < s1; ++j) { uint32_t tmp = d[j]; d[j] = run; run += tmp; }
}

__global__ void k_excl_u32(uint32_t* __restrict__ d, int n, const uint32_t* __restrict__ bsums) {
  __shared__ uint32_t lds[THREADS];
  int b = blockIdx.x, t = threadIdx.x;
  int base = b * CHUNK + t * ITEMS;
  uint32_t v[ITEMS]; uint32_t s = 0;
#pragma unroll
  for (int j = 0; j < ITEMS; ++j) { int i = base + j; uint32_t x = (i < n) ? d[i] : 0u; v[j] = x; s += x; }
  uint32_t run = bsums[b] + block_scan_excl(s, lds);
#pragma unroll
  for (int j = 0; j < ITEMS; ++j) { int i = base + j; if (i < n) d[i] = run; run += v[j]; }
}

// ---------------- edge grouping: 2 stable 10-bit passes on ROW bits ----------------
// hist of (row & 1023) straight from the input row array (64MB read only)
__global__ void k_hist_row(const int* __restrict__ row, int n, int NB, uint32_t* __restrict__ hist) {
  __shared__ uint32_t h[1024];
  int b = blockIdx.x, t = threadIdx.x;
#pragma unroll
  for (int g = 0; g < 4; ++g) h[g * THREADS + t] = 0;
  __syncthreads();
  int base = b * CHUNK;
  for (int j = t; j < CHUNK; j += THREADS) {
    int i = base + j;
    if (i < n) atomicAdd(&h[(uint32_t)row[i] & 1023u], 1u);
  }
  __syncthreads();
#pragma unroll
  for (int g = 0; g < 4; ++g) {
    int d = g * THREADS + t;
    hist[(size_t)d * NB + b] = h[d];
  }
}

// pass 1 fused with packing: read row/col, scatter key=(row<<20|col) by digit=(row&1023)
__global__ __launch_bounds__(THREADS) void k_pack_scatter(
    const int* __restrict__ row, const int* __restrict__ col,
    uint64_t* __restrict__ kout, const uint32_t* __restrict__ hist, int n, int NB) {
  constexpr int DIG = 1024;
  constexpr int G = DIG / THREADS;
  __shared__ uint64_t lkeys[CHUNK];
  __shared__ uint32_t lcnt[DIG];
  __shared__ uint32_t lst[DIG];
  __shared__ uint32_t gofs[DIG];
  __shared__ uint32_t stmp[THREADS];
  __shared__ unsigned short wcnt[4][DIG];
  unsigned short* wflat = &wcnt[0][0];
  int b = blockIdx.x, t = threadIdx.x;
#pragma unroll
  for (int g = 0; g < G; ++g) {
    int d = g * THREADS + t;
    lcnt[d] = 0;
    gofs[d] = hist[(size_t)d * NB + b];
  }
  int lane = t & 63, wid = t >> 6;
  int base = b * CHUNK;
  uint64_t mykey[ITEMS];
  uint32_t myrank[ITEMS];
  __syncthreads();
#pragma unroll
  for (int batch = 0; batch < ITEMS; ++batch) {
    int i = base + batch * THREADS + t;
    bool act = i < n;
    uint64_t key = 0ull;
    uint32_t dig = 0;
    if (act) {
      uint32_t r = (uint32_t)row[i];
      key = ((uint64_t)r << 20) | (uint32_t)col[i];
      dig = r & 1023u;
    }
    mykey[batch] = key;
#pragma unroll
    for (int z = 0; z < 4 * G; ++z) wflat[z * THREADS + t] = 0;
    __syncthreads();
    unsigned long long peers = __ballot(act);
#pragma unroll
    for (int bit = 0; bit < 10; ++bit) {
      unsigned long long m = __ballot(act && ((dig >> bit) & 1u));
      peers &= ((dig >> bit) & 1u) ? m : ~m;
    }
    uint32_t rankw = 0;
    if (act) {
      rankw = (uint32_t)__popcll(peers & ((1ull << lane) - 1ull));
      if (rankw == 0) wcnt[wid][dig] = (unsigned short)__popcll(peers);
    }
    __syncthreads();
    uint32_t pre = 0;
#pragma unroll
    for (int wv = 0; wv < 4; ++wv) if (wv < wid) pre += wcnt[wv][dig];
    myrank[batch] = lcnt[dig] + pre + rankw;
    __syncthreads();
#pragma unroll
    for (int g = 0; g < G; ++g) {
      int d = g * THREADS + t;
      lcnt[d] += (uint32_t)wcnt[0][d] + wcnt[1][d] + wcnt[2][d] + wcnt[3][d];
    }
    __syncthreads();
  }
  uint32_t c[G];
#pragma unroll
  for (int g = 0; g < G; ++g) c[g] = lcnt[G * t + g];
  uint32_t s = 0;
#pragma unroll
  for (int g = 0; g < G; ++g) s += c[g];
  uint32_t tp = block_scan_excl(s, stmp);
#pragma unroll
  for (int g = 0; g < G; ++g) { lst[G * t + g] = tp; tp += c[g]; }
  __syncthreads();
#pragma unroll
  for (int batch = 0; batch < ITEMS; ++batch) {
    int i = base + batch * THREADS + t;
    if (i < n) {
      uint64_t key = mykey[batch];
      uint32_t dig = (uint32_t)(key >> 20) & 1023u;
      lkeys[lst[dig] + myrank[batch]] = key;
    }
  }
  __syncthreads();
  int nloc = n - base; if (nloc > CHUNK) nloc = CHUNK;
  for (int j = t; j < nloc; j += THREADS) {
    uint64_t key = lkeys[j];
    uint32_t dig = (uint32_t)(key >> 20) & 1023u;
    kout[gofs[dig] + ((uint32_t)j - lst[dig])] = key;
  }
}

template <int DBITS>
__global__ void k_rhist64T(const uint64_t* __restrict__ keys, int n, int shift, int NB,
                           uint32_t* __restrict__ hist) {
  constexpr int DIG = 1 << DBITS;
  constexpr int G = DIG / THREADS;
  __shared__ uint32_t h[DIG];
  int b = blockIdx.x, t = threadIdx.x;
#pragma unroll
  for (int g = 0; g < G; ++g) h[g * THREADS + t] = 0;
  __syncthreads();
  int base = b * CHUNK;
  for (int j = t; j < CHUNK; j += THREADS) {
    int i = base + j;
    if (i < n) atomicAdd(&h[(uint32_t)(keys[i] >> shift) & (DIG - 1)], 1u);
  }
  __syncthreads();
#pragma unroll
  for (int g = 0; g < G; ++g) {
    int d = g * THREADS + t;
    hist[(size_t)d * NB + b] = h[d];
  }
}

// Three-phase stable block radix scatter (u64 keys), parameterized digit width.
template <int DBITS>
__global__ __launch_bounds__(THREADS) void k_rscatter64T(
    const uint64_t* __restrict__ kin, uint64_t* __restrict__ kout,
    const uint32_t* __restrict__ hist, int n, int shift, int NB) {
  constexpr int DIG = 1 << DBITS;
  constexpr int G = DIG / THREADS;
  __shared__ uint64_t lkeys[CHUNK];
  __shared__ uint32_t lcnt[DIG];
  __shared__ uint32_t lst[DIG];
  __shared__ uint32_t gofs[DIG];
  __shared__ uint32_t stmp[THREADS];
  __shared__ unsigned short wcnt[4][DIG];
  unsigned short* wflat = &wcnt[0][0];
  int b = blockIdx.x, t = threadIdx.x;
#pragma unroll
  for (int g = 0; g < G; ++g) {
    int d = g * THREADS + t;
    lcnt[d] = 0;
    gofs[d] = hist[(size_t)d * NB + b];
  }
  int lane = t & 63, wid = t >> 6;
  int base = b * CHUNK;
  uint64_t mykey[ITEMS];
  uint32_t myrank[ITEMS];
  __syncthreads();
#pragma unroll
  for (int batch = 0; batch < ITEMS; ++batch) {
    int i = base + batch * THREADS + t;
    bool act = i < n;
    uint64_t key = act ? kin[i] : 0ull;
    mykey[batch] = key;
    uint32_t dig = (uint32_t)(key >> shift) & (DIG - 1);
#pragma unroll
    for (int z = 0; z < 4 * G; ++z) wflat[z * THREADS + t] = 0;
    __syncthreads();
    unsigned long long peers = __ballot(act);
#pragma unroll
    for (int bit = 0; bit < DBITS; ++bit) {
      unsigned long long m = __ballot(act && ((dig >> bit) & 1u));
      peers &= ((dig >> bit) & 1u) ? m : ~m;
    }
    uint32_t rankw = 0;
    if (act) {
      rankw = (uint32_t)__popcll(peers & ((1ull << lane) - 1ull));
      if (rankw == 0) wcnt[wid][dig] = (unsigned short)__popcll(peers);
    }
    __syncthreads();
    uint32_t pre = 0;
#pragma unroll
    for (int wv = 0; wv < 4; ++wv) if (wv < wid) pre += wcnt[wv][dig];
    myrank[batch] = lcnt[dig] + pre + rankw;
    __syncthreads();
#pragma unroll
    for (int g = 0; g < G; ++g) {
      int d = g * THREADS + t;
      lcnt[d] += (uint32_t)wcnt[0][d] + wcnt[1][d] + wcnt[2][d] + wcnt[3][d];
    }
    __syncthreads();
  }
  uint32_t c[G];
#pragma unroll
  for (int g = 0; g < G; ++g) c[g] = lcnt[G * t + g];
  uint32_t s = 0;
#pragma unroll
  for (int g = 0; g < G; ++g) s += c[g];
  uint32_t tp = block_scan_excl(s, stmp);
#pragma unroll
  for (int g = 0; g < G; ++g) { lst[G * t + g] = tp; tp += c[g]; }
  __syncthreads();
#pragma unroll
  for (int batch = 0; batch < ITEMS; ++batch) {
    int i = base + batch * THREADS + t;
    if (i < n) {
      uint64_t key = mykey[batch];
      uint32_t dig = (uint32_t)(key >> shift) & (DIG - 1);
      lkeys[lst[dig] + myrank[batch]] = key;
    }
  }
  __syncthreads();
  int nloc = n - base; if (nloc > CHUNK) nloc = CHUNK;
  for (int j = t; j < nloc; j += THREADS) {
    uint64_t key = lkeys[j];
    uint32_t dig = (uint32_t)(key >> shift) & (DIG - 1);
    kout[gofs[dig] + ((uint32_t)j - lst[dig])] = key;
  }
}

// rowptr[v] = first index i with row(U[i]) >= v; rowptr[Nn] = E
__global__ void k_rowptr(const uint64_t* __restrict__ U, int E, int Nn, int* __restrict__ rowptr) {
  int i = blockIdx.x * blockDim.x + threadIdx.x;
  int st = gridDim.x * blockDim.x;
  for (; i < E; i += st) {
    int r = (int)(U[i] >> 20); if (r > Nn - 1) r = Nn - 1;
    int rp;
    if (i == 0) rp = -1;
    else { rp = (int)(U[i - 1] >> 20); if (rp > Nn - 1) rp = Nn - 1; }
    for (int v = rp + 1; v <= r; ++v) rowptr[v] = i;
    if (i == E - 1) { for (int v = r + 1; v <= Nn; ++v) rowptr[v] = E; }
  }
}

// per-row in-place insertion sort (rows are row-grouped; sorts col within row)
__global__ void k_rowsort(const int* __restrict__ rowptr, int Nn, uint64_t* __restrict__ U) {
  int v = blockIdx.x * blockDim.x + threadIdx.x;
  int st = gridDim.x * blockDim.x;
  for (; v < Nn; v += st) {
    int s = rowptr[v], e = rowptr[v + 1];
    for (int a = s + 1; a < e; ++a) {
      uint64_t key = U[a];
      int b2 = a - 1;
      while (b2 >= s && U[b2] > key) { U[b2 + 1] = U[b2]; --b2; }
      U[b2 + 1] = key;
    }
  }
}

// ---------------- permutation (1M u32 keys + payload), stable LSD radix ----------------
__global__ void k_genbits(uint32_t ka, uint32_t kb, int n,
                          uint32_t* __restrict__ keys, int* __restrict__ vals) {
  int i = blockIdx.x * blockDim.x + threadIdx.x;
  int st = gridDim.x * blockDim.x;
  for (; i < n; i += st) {
    keys[i] = rbits32(ka, kb, (uint32_t)i);
    if (vals) vals[i] = i;
  }
}

template <int DBITS>
__global__ void k_rhistT(const uint32_t* __restrict__ keys, int n, int shift, int NB,
                         uint32_t* __restrict__ hist) {
  constexpr int DIG = 1 << DBITS;
  constexpr int G = DIG / THREADS;
  __shared__ uint32_t h[DIG];
  int b = blockIdx.x, t = threadIdx.x;
#pragma unroll
  for (int g = 0; g < G; ++g) h[g * THREADS + t] = 0;
  __syncthreads();
  int base = b * CHUNK;
  for (int j = t; j < CHUNK; j += THREADS) {
    int i = base + j;
    if (i < n) atomicAdd(&h[(keys[i] >> shift) & (DIG - 1)], 1u);
  }
  __syncthreads();
#pragma unroll
  for (int g = 0; g < G; ++g) {
    int d = g * THREADS + t;
    hist[(size_t)d * NB + b] = h[d];
  }
}

template <int DBITS>
__global__ __launch_bounds__(THREADS) void k_rscatterT(
    const uint32_t* __restrict__ kin, const int* __restrict__ vin,
    uint32_t* __restrict__ kout, int* __restrict__ vout,
    const uint32_t* __restrict__ hist, int n, int shift, int NB) {
  constexpr int DIG = 1 << DBITS;
  constexpr int G = DIG / THREADS;
  __shared__ uint32_t offset[DIG];
  __shared__ unsigned short wcnt[4][DIG];
  unsigned short* wflat = &wcnt[0][0];
  int b = blockIdx.x, t = threadIdx.x;
#pragma unroll
  for (int g = 0; g < G; ++g) {
    int d = g * THREADS + t;
    offset[d] = hist[(size_t)d * NB + b];
  }
  __syncthreads();
  int lane = t & 63, wid = t >> 6;
  int base = b * CHUNK;
  for (int batch = 0; batch < ITEMS; ++batch) {
    int i = base + batch * THREADS + t;
    bool act = i < n;
    uint32_t key = act ? kin[i] : 0u;
    uint32_t dig = (key >> shift) & (DIG - 1);
#pragma unroll
    for (int z = 0; z < 4 * G; ++z) wflat[z * THREADS + t] = 0;
    __syncthreads();
    unsigned long long peers = __ballot(act);
#pragma unroll
    for (int bit = 0; bit < DBITS; ++bit) {
      unsigned long long m = __ballot(act && ((dig >> bit) & 1u));
      peers &= ((dig >> bit) & 1u) ? m : ~m;
    }
    uint32_t rankw = 0;
    if (act) {
      rankw = (uint32_t)__popcll(peers & ((1ull << lane) - 1ull));
      if (rankw == 0) wcnt[wid][dig] = (unsigned short)__popcll(peers);
    }
    __syncthreads();
    if (act) {
      uint32_t pre = 0;
#pragma unroll
      for (int wv = 0; wv < 4; ++wv) if (wv < wid) pre += wcnt[wv][dig];
      uint32_t dst = offset[dig] + pre + rankw;
      kout[dst] = key;
      vout[dst] = vin[i];
    }
    __syncthreads();
#pragma unroll
    for (int g = 0; g < G; ++g) {
      int d = g * THREADS + t;
      offset[d] += (uint32_t)wcnt[0][d] + wcnt[1][d] + wcnt[2][d] + wcnt[3][d];
    }
    __syncthreads();
  }
}

// ---------------- random walks ----------------
__global__ void k_walk(const int* __restrict__ start, int S,
                       const int* __restrict__ rowptr, const uint64_t* __restrict__ U,
                       uint8_t* __restrict__ hits,
                       uint32_t k0a, uint32_t k0b, uint32_t k1a, uint32_t k1b,
                       uint32_t k2a, uint32_t k2b) {
  int i = blockIdx.x * blockDim.x + threadIdx.x;
  int st = gridDim.x * blockDim.x;
  for (; i < S; i += st) {
    int cur = start[i];
    bool active = true;
    uint32_t ka[3] = {k0a, k1a, k2a};
    uint32_t kb[3] = {k0b, k1b, k2b};
#pragma unroll
    for (int s = 0; s < 3; ++s) {
      int rp = rowptr[cur];
      int d = rowptr[cur + 1] - rp;
      bool act = active && (d > 0);
      if (act) hits[cur] = 1;
      uint32_t bits = rbits32(ka[s], kb[s], (uint32_t)i);
      float u = __uint_as_float((bits >> 9) | 0x3f800000u) - 1.0f;  // jax uniform [0,1)
      int off = (int)floorf(u * (float)d);
      int dm1 = d - 1; if (dm1 < 0) dm1 = 0;
      if (off > dm1) off = dm1;
      if (act) cur = (int)(U[rp + off] & COLMASK);
      active = act;
    }
  }
}

// ---------------- outputs (masked edges only exist at i < Nn) ----------------
__global__ void k_mask_copy(const uint8_t* __restrict__ hits, const uint64_t* __restrict__ U,
                            int Nn, uint32_t* __restrict__ bsums, uint64_t* __restrict__ hstage) {
  __shared__ uint32_t lds[THREADS];
  int b = blockIdx.x, t = threadIdx.x;
  int base = b * CHUNK + t * ITEMS;
  uint32_t s = 0;
#pragma unroll
  for (int j = 0; j < ITEMS; ++j) {
    int i = base + j;
    if (i < Nn) { s += (uint32_t)(!hits[i]); hstage[i] = U[i]; }
  }
  lds[t] = s; __syncthreads();
  for (int d2 = THREADS / 2; d2 > 0; d2 >>= 1) { if (t < d2) lds[t] += lds[t + d2]; __syncthreads(); }
  if (t == 0) bsums[b] = lds[0];
}

__global__ void k_out_tail(const uint64_t* __restrict__ U, int E, int Nn,
                           const uint32_t* __restrict__ keephead,
                           int* __restrict__ A, int* __restrict__ B, int* __restrict__ M) {
  int nm = Nn - (int)*keephead;
  int i = Nn + blockIdx.x * blockDim.x + threadIdx.x;
  int st = gridDim.x * blockDim.x;
  for (; i < E; i += st) {
    uint64_t key = U[i];
    A[i - nm] = (int)(key >> 20);
    B[i - nm] = (int)(key & COLMASK);
    M[i] = 1;
  }
}

__global__ void k_out_headCD(const uint64_t* __restrict__ hstage, const uint8_t* __restrict__ hits,
                             int Nn, const uint32_t* __restrict__ bsums,
                             int* __restrict__ A, int* __restrict__ B,
                             int* __restrict__ C, int* __restrict__ D, int* __restrict__ M) {
  __shared__ uint32_t lds[THREADS];
  int b = blockIdx.x, t = threadIdx.x;
  int base = b * CHUNK + t * ITEMS;
  uint32_t keep[ITEMS]; uint32_t s = 0;
#pragma unroll
  for (int j = 0; j < ITEMS; ++j) {
    int i = base + j;
    uint32_t k = (i < Nn) ? (uint32_t)(!hits[i]) : 0u;
    keep[j] = k; s += k;
  }
  uint32_t kr = bsums[b] + block_scan_excl(s, lds);
#pragma unroll
  for (int j = 0; j < ITEMS; ++j) {
    int i = base + j;
    if (i < Nn) {
      uint64_t key = hstage[i];
      if (keep[j]) { A[kr] = (int)(key >> 20); B[kr] = (int)(key & COLMASK); M[i] = 1; ++kr; }
      else { uint32_t mr = (uint32_t)i - kr; C[mr] = (int)(key >> 20); D[mr] = (int)(key & COLMASK); M[i] = 0; }
    }
  }
}

__global__ void k_cdfill(int E, int Nn, const uint32_t* __restrict__ keephead,
                         int* __restrict__ A, int* __restrict__ B,
                         int* __restrict__ C, int* __restrict__ D) {
  int nm = Nn - (int)*keephead;
  int j = blockIdx.x * blockDim.x + threadIdx.x;
  int st = gridDim.x * blockDim.x;
  for (; j < E; j += st) {
    if (j >= nm) { C[j] = -1; D[j] = -1; }
    if (j >= E - nm) { A[j] = -1; B[j] = -1; }
  }
}

// ---------------- launcher ----------------
extern "C" void kernel_launch(void* const* d_in, const int* in_sizes, int n_in,
                              void* d_out, int out_size, void* d_ws, size_t ws_size,
                              hipStream_t stream) {
  const int E = in_sizes[0] / 2;
  const int Nn = 1000000;   // num_nodes (fixed problem)
  const int S = 700000;     // round(0.7*N) * WALKS_PER_NODE
  const int NB_N = (Nn + CHUNK - 1) / CHUNK;  // 245
  const int NB_E = (E + CHUNK - 1) / CHUNK;   // 3907

  const int* row = (const int*)d_in[0];
  const int* col = row + (size_t)E;

  int* out = (int*)d_out;
  int* A = out;                      // final: remaining rows
  int* B = out + (size_t)E;          // final: remaining cols
  int* C = out + (size_t)2 * E;      // final: masked rows
  int* D = out + (size_t)3 * E;      // final: masked cols
  int* M = out + (size_t)4 * E;      // final: edge_mask; staging: perm bufs + hists
  uint64_t* U0 = (uint64_t*)out;                    // spans A+B (128MB)
  uint64_t* U1 = (uint64_t*)(out + (size_t)2 * E);  // spans C+D (128MB)

  // workspace carve (same proven budget as R6)
  char* w = (char*)d_ws;
  uint64_t* hstage = (uint64_t*)w;            // 8,000,000 B (output phase only)
  int* rowptr = (int*)w;                      // 4,000,004 B (aliases hstage; dead after walk)
  w += (size_t)Nn * 8;
  uint8_t* hits = (uint8_t*)w; w += Nn;       // 1,000,000 B
  w = (char*)(((uintptr_t)w + 255) & ~(uintptr_t)255);
  uint32_t* bsums = (uint32_t*)w; w += (size_t)4096 * 4;
  uint32_t* scal = (uint32_t*)w;  w += 64;
  if ((size_t)(w - (char*)d_ws) > ws_size) return;  // insufficient scratch: fail visibly

  // staging inside M region (64 MB): perm bufs [0,16MB), hists at [16MB,32MB)
  uint32_t* pkA = (uint32_t*)M;
  int*      pvA = M + (size_t)Nn;
  uint32_t* pkB = (uint32_t*)(M + (size_t)2 * Nn);
  int*      pvB = M + (size_t)3 * Nn;
  uint32_t* ehist = (uint32_t*)(M + (size_t)4 * Nn);  // up to 16,003,072 B

  // ---- host-side key derivation (JAX threefry, partitionable split = fold_in) ----
  struct KK { uint32_t a, b; };
  auto fold = [](KK k, uint32_t j) { KK r; tf2x32(k.a, k.b, 0u, j, &r.a, &r.b); return r; };
  KK base{0u, 42u};
  KK kperm = fold(base, 0u);
  KK kwalk = fold(base, 1u);
  KK keyA  = fold(kperm, 0u);
  KK sub1  = fold(kperm, 1u);
  KK sub2  = fold(keyA, 1u);
  KK wk0 = fold(kwalk, 0u), wk1 = fold(kwalk, 1u), wk2 = fold(kwalk, 2u);

  auto scan_u32 = [&](uint32_t* d, int n) {
    int SB = (n + CHUNK - 1) / CHUNK;
    k_sums_u32<<<SB, THREADS, 0, stream>>>(d, n, bsums);
    k_scan_single<<<1, THREADS, 0, stream>>>(bsums, SB, (uint32_t*)nullptr);
    k_excl_u32<<<SB, THREADS, 0, stream>>>(d, n, bsums);
  };

  hipMemsetAsync(hits, 0, (size_t)Nn, stream);

  // ---- 1) edge grouping by row: 2 stable 10-bit passes ----
  // pass 1 (digit = row & 1023), hist straight from row[], pack fused into scatter
  k_hist_row<<<NB_E, THREADS, 0, stream>>>(row, E, NB_E, ehist);
  scan_u32(ehist, 1024 * NB_E);
  k_pack_scatter<<<NB_E, THREADS, 0, stream>>>(row, col, U0, ehist, E, NB_E);
  // pass 2 (digit = key>>30 = row high 10 bits), U0 -> U1
  k_rhist64T<10><<<NB_E, THREADS, 0, stream>>>(U0, E, 30, NB_E, ehist);
  scan_u32(ehist, 1024 * NB_E);
  k_rscatter64T<10><<<NB_E, THREADS, 0, stream>>>(U0, U1, ehist, E, 30, NB_E);

  // ---- 2) rowptr, then per-row col sort (lex order complete after this) ----
  k_rowptr<<<4096, THREADS, 0, stream>>>(U1, E, Nn, rowptr);
  k_rowsort<<<NB_N * ITEMS, THREADS, 0, stream>>>(rowptr, Nn, U1);

  // ---- 3) jax.random.permutation(kperm, N): 2 rounds of stable sort by random u32 ----
  auto radix3 = [&](uint32_t* kA, int* vA, uint32_t* kB, int* vB) {
    uint32_t* ki = kA; int* vi = vA; uint32_t* ko = kB; int* vo = vB;
    for (int p = 0; p < 3; ++p) {
      int shift = p * 11;
      k_rhistT<11><<<NB_N, THREADS, 0, stream>>>(ki, Nn, shift, NB_N, ehist);
      scan_u32(ehist, 2048 * NB_N);
      k_rscatterT<11><<<NB_N, THREADS, 0, stream>>>(ki, vi, ko, vo, ehist, Nn, shift, NB_N);
      uint32_t* tk = ki; ki = ko; ko = tk;
      int* tv = vi; vi = vo; vo = tv;
    }
  };
  // 3 passes end back in the B buffers, so generate into pkB/pvB to finish in pkA/pvA
  k_genbits<<<2048, THREADS, 0, stream>>>(sub1.a, sub1.b, Nn, pkB, pvB);
  radix3(pkB, pvB, pkA, pvA);  // odd #passes: ends in (pkA, pvA)
  k_genbits<<<2048, THREADS, 0, stream>>>(sub2.a, sub2.b, Nn, pkB, (int*)nullptr);
  radix3(pkB, pvA, pkA, pvB);  // keys fresh in pkB, payload = perm in pvA; ends in (pkA, pvB)
  int* permv = pvB;

  // ---- 4) random walks: mark hit nodes ----
  k_walk<<<(S + THREADS - 1) / THREADS, THREADS, 0, stream>>>(
      permv, S, rowptr, U1, hits, wk0.a, wk0.b, wk1.a, wk1.b, wk2.a, wk2.b);

  // ---- 5) outputs: copy head + keep-scan, tail shift, head compaction, -1 fills ----
  k_mask_copy<<<NB_N, THREADS, 0, stream>>>(hits, U1, Nn, bsums, hstage);
  k_scan_single<<<1, THREADS, 0, stream>>>(bsums, NB_N, &scal[0]);   // scal[0] = keeps among i<Nn
  k_out_tail<<<4096, THREADS, 0, stream>>>(U1, E, Nn, &scal[0], A, B, M);
  k_out_headCD<<<NB_N, THREADS, 0, stream>>>(hstage, hits, Nn, bsums, A, B, C, D, M);
  k_cdfill<<<4096, THREADS, 0, stream>>>(E, Nn, &scal[0], A, B, C, D);
}

// Round 8
// 1438.599 us; speedup vs baseline: 1.5415x; 1.5415x over previous
//
#include <hip/hip_runtime.h>
#include <stdint.h>

#define THREADS 256
#define ITEMS 16
#define CHUNK (THREADS * ITEMS)
#define COLMASK 0xFFFFFu
#define RS_CAP 4608   // LDS rowsort segment capacity (u64): mean 4096, +8 sigma

// ---------------- threefry2x32, JAX-compatible (20 rounds) ----------------
__host__ __device__ static inline void tf2x32(uint32_t k0, uint32_t k1,
                                              uint32_t x0, uint32_t x1,
                                              uint32_t* o0, uint32_t* o1) {
  uint32_t ks[3] = {k0, k1, k0 ^ k1 ^ 0x1BD11BDAu};
  x0 += ks[0]; x1 += ks[1];
  const uint32_t RA[4] = {13u, 15u, 26u, 6u};
  const uint32_t RB[4] = {17u, 29u, 16u, 24u};
#pragma unroll
  for (int g = 0; g < 5; ++g) {
    const uint32_t* R = (g & 1) ? RB : RA;
#pragma unroll
    for (int j = 0; j < 4; ++j) {
      x0 += x1;
      x1 = (x1 << R[j]) | (x1 >> (32u - R[j]));
      x1 ^= x0;
    }
    x0 += ks[(g + 1) % 3];
    x1 += ks[(g + 2) % 3] + (uint32_t)(g + 1);
  }
  *o0 = x0; *o1 = x1;
}

__device__ static inline uint32_t rbits32(uint32_t ka, uint32_t kb, uint32_t i) {
  uint32_t o0, o1;
  tf2x32(ka, kb, 0u, i, &o0, &o1);
  return o0 ^ o1;
}

// bijective XCD-aware block swizzle (m204 variant; works for any nwg)
__device__ static inline int xcd_swz(int orig, int nwg) {
  int q = nwg >> 3, r = nwg & 7;
  int xcd = orig & 7, idx = orig >> 3;
  return (xcd < r ? xcd * (q + 1) : r * (q + 1) + (xcd - r) * q) + idx;
}

// ---------------- block exclusive scan (all threads must call) ----------------
__device__ static inline uint32_t block_scan_excl(uint32_t v, uint32_t* lds) {
  int t = threadIdx.x;
  lds[t] = v;
  __syncthreads();
#pragma unroll
  for (int d = 1; d < THREADS; d <<= 1) {
    uint32_t add = (t >= d) ? lds[t - d] : 0u;
    __syncthreads();
    lds[t] += add;
    __syncthreads();
  }
  return lds[t] - v;
}

// ---------------- hierarchical scan helpers ----------------
__global__ void k_sums_u32(const uint32_t* __restrict__ d, int n, uint32_t* __restrict__ bsums) {
  __shared__ uint32_t lds[THREADS];
  int b = blockIdx.x, t = threadIdx.x;
  int base = b * CHUNK + t * ITEMS;
  uint32_t s = 0;
#pragma unroll
  for (int j = 0; j < ITEMS; ++j) { int i = base + j; if (i < n) s += d[i]; }
  lds[t] = s; __syncthreads();
  for (int d2 = THREADS / 2; d2 > 0; d2 >>= 1) { if (t < d2) lds[t] += lds[t + d2]; __syncthreads(); }
  if (t == 0) bsums[b] = lds[0];
}

__global__ void k_scan_single(uint32_t* __restrict__ d, int n, uint32_t* __restrict__ total_out) {
  __shared__ uint32_t lds[THREADS];
  int t = threadIdx.x;
  int K = (n + THREADS - 1) / THREADS;
  int s0 = t * K, s1 = (s0 + K < n) ? (s0 + K) : n;
  uint32_t s = 0;
  for (int j = s0; j < s1; ++j) s += d[j];
  lds[t] = s; __syncthreads();
#pragma unroll
  for (int dd = 1; dd < THREADS; dd <<= 1) {
    uint32_t a = (t >= dd) ? lds[t - dd] : 0u;
    __syncthreads();
    lds[t] += a;
    __syncthreads();
  }
  uint32_t incl = lds[t];
  if (total_out && t == THREADS - 1) *total_out = incl;
  uint32_t run = incl - s;
  for (int j = s0; j < s1; ++j) { uint32_t tmp = d[j]; d[j] = run; run += tmp; }
}

__global__ void k_excl_u32(uint32_t* __restrict__ d, int n, const uint32_t* __restrict__ bsums) {
  __shared__ uint32_t lds[THREADS];
  int b = blockIdx.x, t = threadIdx.x;
  int base = b * CHUNK + t * ITEMS;
  uint32_t v[ITEMS]; uint32_t s = 0;
#pragma unroll
  for (int j = 0; j < ITEMS; ++j) { int i = base + j; uint32_t x = (i < n) ? d[i] : 0u; v[j] = x; s += x; }
  uint32_t run = bsums[b] + block_scan_excl(s, lds);
#pragma unroll
  for (int j = 0; j < ITEMS; ++j) { int i = base + j; if (i < n) d[i] = run; run += v[j]; }
}

// ---------------- edge grouping: 2 stable 10-bit passes on ROW bits ----------------
__global__ void k_hist_row(const int* __restrict__ row, int n, int NB, uint32_t* __restrict__ hist) {
  __shared__ uint32_t h[1024];
  int b = blockIdx.x, t = threadIdx.x;
#pragma unroll
  for (int g = 0; g < 4; ++g) h[g * THREADS + t] = 0;
  __syncthreads();
  int base = b * CHUNK;
  for (int j = t; j < CHUNK; j += THREADS) {
    int i = base + j;
    if (i < n) atomicAdd(&h[(uint32_t)row[i] & 1023u], 1u);
  }
  __syncthreads();
#pragma unroll
  for (int g = 0; g < 4; ++g) {
    int d = g * THREADS + t;
    hist[(size_t)d * NB + b] = h[d];
  }
}

// pass 1 fused with packing: read row/col, scatter key=(row<<20|col) by digit=(row&1023)
__global__ __launch_bounds__(THREADS) void k_pack_scatter(
    const int* __restrict__ row, const int* __restrict__ col,
    uint64_t* __restrict__ kout, const uint32_t* __restrict__ hist, int n, int NB) {
  constexpr int DIG = 1024;
  constexpr int G = DIG / THREADS;
  __shared__ uint64_t lkeys[CHUNK];
  __shared__ uint32_t lcnt[DIG];
  __shared__ uint32_t lst[DIG];
  __shared__ uint32_t gofs[DIG];
  __shared__ uint32_t stmp[THREADS];
  __shared__ unsigned short wcnt[4][DIG];
  unsigned short* wflat = &wcnt[0][0];
  int b = xcd_swz(blockIdx.x, gridDim.x), t = threadIdx.x;
#pragma unroll
  for (int g = 0; g < G; ++g) {
    int d = g * THREADS + t;
    lcnt[d] = 0;
    gofs[d] = hist[(size_t)d * NB + b];
  }
  int lane = t & 63, wid = t >> 6;
  int base = b * CHUNK;
  uint64_t mykey[ITEMS];
  uint32_t myrank[ITEMS];
  __syncthreads();
#pragma unroll
  for (int batch = 0; batch < ITEMS; ++batch) {
    int i = base + batch * THREADS + t;
    bool act = i < n;
    uint64_t key = 0ull;
    uint32_t dig = 0;
    if (act) {
      uint32_t r = (uint32_t)row[i];
      key = ((uint64_t)r << 20) | (uint32_t)col[i];
      dig = r & 1023u;
    }
    mykey[batch] = key;
#pragma unroll
    for (int z = 0; z < 4 * G; ++z) wflat[z * THREADS + t] = 0;
    __syncthreads();
    unsigned long long peers = __ballot(act);
#pragma unroll
    for (int bit = 0; bit < 10; ++bit) {
      unsigned long long m = __ballot(act && ((dig >> bit) & 1u));
      peers &= ((dig >> bit) & 1u) ? m : ~m;
    }
    uint32_t rankw = 0;
    if (act) {
      rankw = (uint32_t)__popcll(peers & ((1ull << lane) - 1ull));
      if (rankw == 0) wcnt[wid][dig] = (unsigned short)__popcll(peers);
    }
    __syncthreads();
    uint32_t pre = 0;
#pragma unroll
    for (int wv = 0; wv < 4; ++wv) if (wv < wid) pre += wcnt[wv][dig];
    myrank[batch] = lcnt[dig] + pre + rankw;
    __syncthreads();
#pragma unroll
    for (int g = 0; g < G; ++g) {
      int d = g * THREADS + t;
      lcnt[d] += (uint32_t)wcnt[0][d] + wcnt[1][d] + wcnt[2][d] + wcnt[3][d];
    }
    __syncthreads();
  }
  uint32_t c[G];
#pragma unroll
  for (int g = 0; g < G; ++g) c[g] = lcnt[G * t + g];
  uint32_t s = 0;
#pragma unroll
  for (int g = 0; g < G; ++g) s += c[g];
  uint32_t tp = block_scan_excl(s, stmp);
#pragma unroll
  for (int g = 0; g < G; ++g) { lst[G * t + g] = tp; tp += c[g]; }
  __syncthreads();
#pragma unroll
  for (int batch = 0; batch < ITEMS; ++batch) {
    int i = base + batch * THREADS + t;
    if (i < n) {
      uint64_t key = mykey[batch];
      uint32_t dig = (uint32_t)(key >> 20) & 1023u;
      lkeys[lst[dig] + myrank[batch]] = key;
    }
  }
  __syncthreads();
  int nloc = n - base; if (nloc > CHUNK) nloc = CHUNK;
  for (int j = t; j < nloc; j += THREADS) {
    uint64_t key = lkeys[j];
    uint32_t dig = (uint32_t)(key >> 20) & 1023u;
    kout[gofs[dig] + ((uint32_t)j - lst[dig])] = key;
  }
}

template <int DBITS>
__global__ void k_rhist64T(const uint64_t* __restrict__ keys, int n, int shift, int NB,
                           uint32_t* __restrict__ hist) {
  constexpr int DIG = 1 << DBITS;
  constexpr int G = DIG / THREADS;
  __shared__ uint32_t h[DIG];
  int b = blockIdx.x, t = threadIdx.x;
#pragma unroll
  for (int g = 0; g < G; ++g) h[g * THREADS + t] = 0;
  __syncthreads();
  int base = b * CHUNK;
  for (int j = t; j < CHUNK; j += THREADS) {
    int i = base + j;
    if (i < n) atomicAdd(&h[(uint32_t)(keys[i] >> shift) & (DIG - 1)], 1u);
  }
  __syncthreads();
#pragma unroll
  for (int g = 0; g < G; ++g) {
    int d = g * THREADS + t;
    hist[(size_t)d * NB + b] = h[d];
  }
}

// Three-phase stable block radix scatter (u64 keys), parameterized digit width.
template <int DBITS>
__global__ __launch_bounds__(THREADS) void k_rscatter64T(
    const uint64_t* __restrict__ kin, uint64_t* __restrict__ kout,
    const uint32_t* __restrict__ hist, int n, int shift, int NB) {
  constexpr int DIG = 1 << DBITS;
  constexpr int G = DIG / THREADS;
  __shared__ uint64_t lkeys[CHUNK];
  __shared__ uint32_t lcnt[DIG];
  __shared__ uint32_t lst[DIG];
  __shared__ uint32_t gofs[DIG];
  __shared__ uint32_t stmp[THREADS];
  __shared__ unsigned short wcnt[4][DIG];
  unsigned short* wflat = &wcnt[0][0];
  int b = xcd_swz(blockIdx.x, gridDim.x), t = threadIdx.x;
#pragma unroll
  for (int g = 0; g < G; ++g) {
    int d = g * THREADS + t;
    lcnt[d] = 0;
    gofs[d] = hist[(size_t)d * NB + b];
  }
  int lane = t & 63, wid = t >> 6;
  int base = b * CHUNK;
  uint64_t mykey[ITEMS];
  uint32_t myrank[ITEMS];
  __syncthreads();
#pragma unroll
  for (int batch = 0; batch < ITEMS; ++batch) {
    int i = base + batch * THREADS + t;
    bool act = i < n;
    uint64_t key = act ? kin[i] : 0ull;
    mykey[batch] = key;
    uint32_t dig = (uint32_t)(key >> shift) & (DIG - 1);
#pragma unroll
    for (int z = 0; z < 4 * G; ++z) wflat[z * THREADS + t] = 0;
    __syncthreads();
    unsigned long long peers = __ballot(act);
#pragma unroll
    for (int bit = 0; bit < DBITS; ++bit) {
      unsigned long long m = __ballot(act && ((dig >> bit) & 1u));
      peers &= ((dig >> bit) & 1u) ? m : ~m;
    }
    uint32_t rankw = 0;
    if (act) {
      rankw = (uint32_t)__popcll(peers & ((1ull << lane) - 1ull));
      if (rankw == 0) wcnt[wid][dig] = (unsigned short)__popcll(peers);
    }
    __syncthreads();
    uint32_t pre = 0;
#pragma unroll
    for (int wv = 0; wv < 4; ++wv) if (wv < wid) pre += wcnt[wv][dig];
    myrank[batch] = lcnt[dig] + pre + rankw;
    __syncthreads();
#pragma unroll
    for (int g = 0; g < G; ++g) {
      int d = g * THREADS + t;
      lcnt[d] += (uint32_t)wcnt[0][d] + wcnt[1][d] + wcnt[2][d] + wcnt[3][d];
    }
    __syncthreads();
  }
  uint32_t c[G];
#pragma unroll
  for (int g = 0; g < G; ++g) c[g] = lcnt[G * t + g];
  uint32_t s = 0;
#pragma unroll
  for (int g = 0; g < G; ++g) s += c[g];
  uint32_t tp = block_scan_excl(s, stmp);
#pragma unroll
  for (int g = 0; g < G; ++g) { lst[G * t + g] = tp; tp += c[g]; }
  __syncthreads();
#pragma unroll
  for (int batch = 0; batch < ITEMS; ++batch) {
    int i = base + batch * THREADS + t;
    if (i < n) {
      uint64_t key = mykey[batch];
      uint32_t dig = (uint32_t)(key >> shift) & (DIG - 1);
      lkeys[lst[dig] + myrank[batch]] = key;
    }
  }
  __syncthreads();
  int nloc = n - base; if (nloc > CHUNK) nloc = CHUNK;
  for (int j = t; j < nloc; j += THREADS) {
    uint64_t key = lkeys[j];
    uint32_t dig = (uint32_t)(key >> shift) & (DIG - 1);
    kout[gofs[dig] + ((uint32_t)j - lst[dig])] = key;
  }
}

// rowptr[v] = first index i with row(U[i]) >= v; rowptr[Nn] = E
__global__ void k_rowptr(const uint64_t* __restrict__ U, int E, int Nn, int* __restrict__ rowptr) {
  int i = blockIdx.x * blockDim.x + threadIdx.x;
  int st = gridDim.x * blockDim.x;
  for (; i < E; i += st) {
    int r = (int)(U[i] >> 20); if (r > Nn - 1) r = Nn - 1;
    int rp;
    if (i == 0) rp = -1;
    else { rp = (int)(U[i - 1] >> 20); if (rp > Nn - 1) rp = Nn - 1; }
    for (int v = rp + 1; v <= r; ++v) rowptr[v] = i;
    if (i == E - 1) { for (int v = r + 1; v <= Nn; ++v) rowptr[v] = E; }
  }
}

// per-row col sort in LDS: one WG = 256 consecutive rows (avg 4096 keys).
// Load segment coalesced -> per-thread insertion sort in LDS -> store coalesced.
// Fallback (essentially never taken): global-memory insertion if segment > RS_CAP.
__global__ __launch_bounds__(THREADS) void k_rowsort_lds(
    const int* __restrict__ rowptr, int Nn, uint64_t* __restrict__ U) {
  __shared__ uint64_t lbuf[RS_CAP];
  int b = blockIdx.x, t = threadIdx.x;
  int r0 = b * THREADS;
  int r1 = r0 + THREADS; if (r1 > Nn) r1 = Nn;
  if (r0 >= Nn) return;
  int s = rowptr[r0], e = rowptr[r1];
  int nseg = e - s;
  int r = r0 + t;
  if (nseg <= RS_CAP) {
    for (int j = t; j < nseg; j += THREADS) lbuf[j] = U[s + j];
    __syncthreads();
    if (r < Nn) {
      int a0 = rowptr[r] - s, a1 = rowptr[r + 1] - s;
      for (int a = a0 + 1; a < a1; ++a) {
        uint64_t key = lbuf[a];
        int b2 = a - 1;
        while (b2 >= a0 && lbuf[b2] > key) { lbuf[b2 + 1] = lbuf[b2]; --b2; }
        lbuf[b2 + 1] = key;
      }
    }
    __syncthreads();
    for (int j = t; j < nseg; j += THREADS) U[s + j] = lbuf[j];
  } else {
    if (r < Nn) {
      int a0 = rowptr[r], a1 = rowptr[r + 1];
      for (int a = a0 + 1; a < a1; ++a) {
        uint64_t key = U[a];
        int b2 = a - 1;
        while (b2 >= a0 && U[b2] > key) { U[b2 + 1] = U[b2]; --b2; }
        U[b2 + 1] = key;
      }
    }
  }
}

// ---------------- permutation (1M u32 keys + payload), stable LSD radix ----------------
__global__ void k_genbits(uint32_t ka, uint32_t kb, int n,
                          uint32_t* __restrict__ keys, int* __restrict__ vals) {
  int i = blockIdx.x * blockDim.x + threadIdx.x;
  int st = gridDim.x * blockDim.x;
  for (; i < n; i += st) {
    keys[i] = rbits32(ka, kb, (uint32_t)i);
    if (vals) vals[i] = i;
  }
}

template <int DBITS>
__global__ void k_rhistT(const uint32_t* __restrict__ keys, int n, int shift, int NB,
                         uint32_t* __restrict__ hist) {
  constexpr int DIG = 1 << DBITS;
  constexpr int G = DIG / THREADS;
  __shared__ uint32_t h[DIG];
  int b = blockIdx.x, t = threadIdx.x;
#pragma unroll
  for (int g = 0; g < G; ++g) h[g * THREADS + t] = 0;
  __syncthreads();
  int base = b * CHUNK;
  for (int j = t; j < CHUNK; j += THREADS) {
    int i = base + j;
    if (i < n) atomicAdd(&h[(keys[i] >> shift) & (DIG - 1)], 1u);
  }
  __syncthreads();
#pragma unroll
  for (int g = 0; g < G; ++g) {
    int d = g * THREADS + t;
    hist[(size_t)d * NB + b] = h[d];
  }
}

template <int DBITS>
__global__ __launch_bounds__(THREADS) void k_rscatterT(
    const uint32_t* __restrict__ kin, const int* __restrict__ vin,
    uint32_t* __restrict__ kout, int* __restrict__ vout,
    const uint32_t* __restrict__ hist, int n, int shift, int NB) {
  constexpr int DIG = 1 << DBITS;
  constexpr int G = DIG / THREADS;
  __shared__ uint32_t offset[DIG];
  __shared__ unsigned short wcnt[4][DIG];
  unsigned short* wflat = &wcnt[0][0];
  int b = blockIdx.x, t = threadIdx.x;
#pragma unroll
  for (int g = 0; g < G; ++g) {
    int d = g * THREADS + t;
    offset[d] = hist[(size_t)d * NB + b];
  }
  __syncthreads();
  int lane = t & 63, wid = t >> 6;
  int base = b * CHUNK;
  for (int batch = 0; batch < ITEMS; ++batch) {
    int i = base + batch * THREADS + t;
    bool act = i < n;
    uint32_t key = act ? kin[i] : 0u;
    uint32_t dig = (key >> shift) & (DIG - 1);
#pragma unroll
    for (int z = 0; z < 4 * G; ++z) wflat[z * THREADS + t] = 0;
    __syncthreads();
    unsigned long long peers = __ballot(act);
#pragma unroll
    for (int bit = 0; bit < DBITS; ++bit) {
      unsigned long long m = __ballot(act && ((dig >> bit) & 1u));
      peers &= ((dig >> bit) & 1u) ? m : ~m;
    }
    uint32_t rankw = 0;
    if (act) {
      rankw = (uint32_t)__popcll(peers & ((1ull << lane) - 1ull));
      if (rankw == 0) wcnt[wid][dig] = (unsigned short)__popcll(peers);
    }
    __syncthreads();
    if (act) {
      uint32_t pre = 0;
#pragma unroll
      for (int wv = 0; wv < 4; ++wv) if (wv < wid) pre += wcnt[wv][dig];
      uint32_t dst = offset[dig] + pre + rankw;
      kout[dst] = key;
      vout[dst] = vin[i];
    }
    __syncthreads();
#pragma unroll
    for (int g = 0; g < G; ++g) {
      int d = g * THREADS + t;
      offset[d] += (uint32_t)wcnt[0][d] + wcnt[1][d] + wcnt[2][d] + wcnt[3][d];
    }
    __syncthreads();
  }
}

// ---------------- random walks ----------------
__global__ void k_walk(const int* __restrict__ start, int S,
                       const int* __restrict__ rowptr, const uint64_t* __restrict__ U,
                       uint8_t* __restrict__ hits,
                       uint32_t k0a, uint32_t k0b, uint32_t k1a, uint32_t k1b,
                       uint32_t k2a, uint32_t k2b) {
  int i = blockIdx.x * blockDim.x + threadIdx.x;
  int st = gridDim.x * blockDim.x;
  for (; i < S; i += st) {
    int cur = start[i];
    bool active = true;
    uint32_t ka[3] = {k0a, k1a, k2a};
    uint32_t kb[3] = {k0b, k1b, k2b};
#pragma unroll
    for (int s = 0; s < 3; ++s) {
      int rp = rowptr[cur];
      int d = rowptr[cur + 1] - rp;
      bool act = active && (d > 0);
      if (act) hits[cur] = 1;
      uint32_t bits = rbits32(ka[s], kb[s], (uint32_t)i);
      float u = __uint_as_float((bits >> 9) | 0x3f800000u) - 1.0f;  // jax uniform [0,1)
      int off = (int)floorf(u * (float)d);
      int dm1 = d - 1; if (dm1 < 0) dm1 = 0;
      if (off > dm1) off = dm1;
      if (act) cur = (int)(U[rp + off] & COLMASK);
      active = act;
    }
  }
}

// ---------------- outputs (masked edges only exist at i < Nn) ----------------
__global__ void k_mask_copy(const uint8_t* __restrict__ hits, const uint64_t* __restrict__ U,
                            int Nn, uint32_t* __restrict__ bsums, uint64_t* __restrict__ hstage) {
  __shared__ uint32_t lds[THREADS];
  int b = blockIdx.x, t = threadIdx.x;
  int base = b * CHUNK + t * ITEMS;
  uint32_t s = 0;
#pragma unroll
  for (int j = 0; j < ITEMS; ++j) {
    int i = base + j;
    if (i < Nn) { s += (uint32_t)(!hits[i]); hstage[i] = U[i]; }
  }
  lds[t] = s; __syncthreads();
  for (int d2 = THREADS / 2; d2 > 0; d2 >>= 1) { if (t < d2) lds[t] += lds[t + d2]; __syncthreads(); }
  if (t == 0) bsums[b] = lds[0];
}

__global__ void k_out_tail(const uint64_t* __restrict__ U, int E, int Nn,
                           const uint32_t* __restrict__ keephead,
                           int* __restrict__ A, int* __restrict__ B, int* __restrict__ M) {
  int nm = Nn - (int)*keephead;
  int i = Nn + blockIdx.x * blockDim.x + threadIdx.x;
  int st = gridDim.x * blockDim.x;
  for (; i < E; i += st) {
    uint64_t key = U[i];
    A[i - nm] = (int)(key >> 20);
    B[i - nm] = (int)(key & COLMASK);
    M[i] = 1;
  }
}

__global__ void k_out_headCD(const uint64_t* __restrict__ hstage, const uint8_t* __restrict__ hits,
                             int Nn, const uint32_t* __restrict__ bsums,
                             int* __restrict__ A, int* __restrict__ B,
                             int* __restrict__ C, int* __restrict__ D, int* __restrict__ M) {
  __shared__ uint32_t lds[THREADS];
  int b = blockIdx.x, t = threadIdx.x;
  int base = b * CHUNK + t * ITEMS;
  uint32_t keep[ITEMS]; uint32_t s = 0;
#pragma unroll
  for (int j = 0; j < ITEMS; ++j) {
    int i = base + j;
    uint32_t k = (i < Nn) ? (uint32_t)(!hits[i]) : 0u;
    keep[j] = k; s += k;
  }
  uint32_t kr = bsums[b] + block_scan_excl(s, lds);
#pragma unroll
  for (int j = 0; j < ITEMS; ++j) {
    int i = base + j;
    if (i < Nn) {
      uint64_t key = hstage[i];
      if (keep[j]) { A[kr] = (int)(key >> 20); B[kr] = (int)(key & COLMASK); M[i] = 1; ++kr; }
      else { uint32_t mr = (uint32_t)i - kr; C[mr] = (int)(key >> 20); D[mr] = (int)(key & COLMASK); M[i] = 0; }
    }
  }
}

__global__ void k_cdfill(int E, int Nn, const uint32_t* __restrict__ keephead,
                         int* __restrict__ A, int* __restrict__ B,
                         int* __restrict__ C, int* __restrict__ D) {
  int nm = Nn - (int)*keephead;
  int j = blockIdx.x * blockDim.x + threadIdx.x;
  int st = gridDim.x * blockDim.x;
  for (; j < E; j += st) {
    if (j >= nm) { C[j] = -1; D[j] = -1; }
    if (j >= E - nm) { A[j] = -1; B[j] = -1; }
  }
}

// ---------------- launcher ----------------
extern "C" void kernel_launch(void* const* d_in, const int* in_sizes, int n_in,
                              void* d_out, int out_size, void* d_ws, size_t ws_size,
                              hipStream_t stream) {
  const int E = in_sizes[0] / 2;
  const int Nn = 1000000;   // num_nodes (fixed problem)
  const int S = 700000;     // round(0.7*N) * WALKS_PER_NODE
  const int NB_N = (Nn + CHUNK - 1) / CHUNK;  // 245
  const int NB_E = (E + CHUNK - 1) / CHUNK;   // 3907
  const int NB_R = (Nn + THREADS - 1) / THREADS;  // 3907 rowsort WGs

  const int* row = (const int*)d_in[0];
  const int* col = row + (size_t)E;

  int* out = (int*)d_out;
  int* A = out;                      // final: remaining rows
  int* B = out + (size_t)E;          // final: remaining cols
  int* C = out + (size_t)2 * E;      // final: masked rows
  int* D = out + (size_t)3 * E;      // final: masked cols
  int* M = out + (size_t)4 * E;      // final: edge_mask; staging: perm bufs + hists
  uint64_t* U0 = (uint64_t*)out;                    // spans A+B (128MB)
  uint64_t* U1 = (uint64_t*)(out + (size_t)2 * E);  // spans C+D (128MB)

  // workspace carve (same proven budget)
  char* w = (char*)d_ws;
  uint64_t* hstage = (uint64_t*)w;            // 8,000,000 B (output phase only)
  int* rowptr = (int*)w;                      // 4,000,004 B (aliases hstage; dead after walk)
  w += (size_t)Nn * 8;
  uint8_t* hits = (uint8_t*)w; w += Nn;       // 1,000,000 B
  w = (char*)(((uintptr_t)w + 255) & ~(uintptr_t)255);
  uint32_t* bsums = (uint32_t*)w; w += (size_t)4096 * 4;
  uint32_t* scal = (uint32_t*)w;  w += 64;
  if ((size_t)(w - (char*)d_ws) > ws_size) return;  // insufficient scratch: fail visibly

  // staging inside M region (64 MB): perm bufs [0,16MB), hists at [16MB,32MB)
  uint32_t* pkA = (uint32_t*)M;
  int*      pvA = M + (size_t)Nn;
  uint32_t* pkB = (uint32_t*)(M + (size_t)2 * Nn);
  int*      pvB = M + (size_t)3 * Nn;
  uint32_t* ehist = (uint32_t*)(M + (size_t)4 * Nn);  // up to 16,003,072 B

  // ---- host-side key derivation (JAX threefry, partitionable split = fold_in) ----
  struct KK { uint32_t a, b; };
  auto fold = [](KK k, uint32_t j) { KK r; tf2x32(k.a, k.b, 0u, j, &r.a, &r.b); return r; };
  KK base{0u, 42u};
  KK kperm = fold(base, 0u);
  KK kwalk = fold(base, 1u);
  KK keyA  = fold(kperm, 0u);
  KK sub1  = fold(kperm, 1u);
  KK sub2  = fold(keyA, 1u);
  KK wk0 = fold(kwalk, 0u), wk1 = fold(kwalk, 1u), wk2 = fold(kwalk, 2u);

  auto scan_u32 = [&](uint32_t* d, int n) {
    int SB = (n + CHUNK - 1) / CHUNK;
    k_sums_u32<<<SB, THREADS, 0, stream>>>(d, n, bsums);
    k_scan_single<<<1, THREADS, 0, stream>>>(bsums, SB, (uint32_t*)nullptr);
    k_excl_u32<<<SB, THREADS, 0, stream>>>(d, n, bsums);
  };

  hipMemsetAsync(hits, 0, (size_t)Nn, stream);

  // ---- 1) edge grouping by row: 2 stable 10-bit passes ----
  k_hist_row<<<NB_E, THREADS, 0, stream>>>(row, E, NB_E, ehist);
  scan_u32(ehist, 1024 * NB_E);
  k_pack_scatter<<<NB_E, THREADS, 0, stream>>>(row, col, U0, ehist, E, NB_E);
  k_rhist64T<10><<<NB_E, THREADS, 0, stream>>>(U0, E, 30, NB_E, ehist);
  scan_u32(ehist, 1024 * NB_E);
  k_rscatter64T<10><<<NB_E, THREADS, 0, stream>>>(U0, U1, ehist, E, 30, NB_E);

  // ---- 2) rowptr, then per-row col sort in LDS (lex order complete after this) ----
  k_rowptr<<<4096, THREADS, 0, stream>>>(U1, E, Nn, rowptr);
  k_rowsort_lds<<<NB_R, THREADS, 0, stream>>>(rowptr, Nn, U1);

  // ---- 3) jax.random.permutation(kperm, N): 2 rounds of stable sort by random u32 ----
  auto radix3 = [&](uint32_t* kA, int* vA, uint32_t* kB, int* vB) {
    uint32_t* ki = kA; int* vi = vA; uint32_t* ko = kB; int* vo = vB;
    for (int p = 0; p < 3; ++p) {
      int shift = p * 11;
      k_rhistT<11><<<NB_N, THREADS, 0, stream>>>(ki, Nn, shift, NB_N, ehist);
      scan_u32(ehist, 2048 * NB_N);
      k_rscatterT<11><<<NB_N, THREADS, 0, stream>>>(ki, vi, ko, vo, ehist, Nn, shift, NB_N);
      uint32_t* tk = ki; ki = ko; ko = tk;
      int* tv = vi; vi = vo; vo = tv;
    }
  };
  k_genbits<<<2048, THREADS, 0, stream>>>(sub1.a, sub1.b, Nn, pkB, pvB);
  radix3(pkB, pvB, pkA, pvA);  // odd #passes: ends in (pkA, pvA)
  k_genbits<<<2048, THREADS, 0, stream>>>(sub2.a, sub2.b, Nn, pkB, (int*)nullptr);
  radix3(pkB, pvA, pkA, pvB);  // keys fresh in pkB, payload = perm in pvA; ends in (pkA, pvB)
  int* permv = pvB;

  // ---- 4) random walks: mark hit nodes ----
  k_walk<<<(S + THREADS - 1) / THREADS, THREADS, 0, stream>>>(
      permv, S, rowptr, U1, hits, wk0.a, wk0.b, wk1.a, wk1.b, wk2.a, wk2.b);

  // ---- 5) outputs: copy head + keep-scan, tail shift, head compaction, -1 fills ----
  k_mask_copy<<<NB_N, THREADS, 0, stream>>>(hits, U1, Nn, bsums, hstage);
  k_scan_single<<<1, THREADS, 0, stream>>>(bsums, NB_N, &scal[0]);   // scal[0] = keeps among i<Nn
  k_out_tail<<<4096, THREADS, 0, stream>>>(U1, E, Nn, &scal[0], A, B, M);
  k_out_headCD<<<NB_N, THREADS, 0, stream>>>(hstage, hits, Nn, bsums, A, B, C, D, M);
  k_cdfill<<<4096, THREADS, 0, stream>>>(E, Nn, &scal[0], A, B, C, D);
}

// Round 9
// 1305.188 us; speedup vs baseline: 1.6990x; 1.1022x over previous
//
#include <hip/hip_runtime.h>
#include <stdint.h>

#define THREADS 256
#define ITEMS 16
#define CHUNK (THREADS * ITEMS)
#define COLMASK 0xFFFFFu
#define RS_CAP 4608   // LDS rowsort segment capacity (u64): mean 4096, +8 sigma

// ---------------- threefry2x32, JAX-compatible (20 rounds) ----------------
__host__ __device__ static inline void tf2x32(uint32_t k0, uint32_t k1,
                                              uint32_t x0, uint32_t x1,
                                              uint32_t* o0, uint32_t* o1) {
  uint32_t ks[3] = {k0, k1, k0 ^ k1 ^ 0x1BD11BDAu};
  x0 += ks[0]; x1 += ks[1];
  const uint32_t RA[4] = {13u, 15u, 26u, 6u};
  const uint32_t RB[4] = {17u, 29u, 16u, 24u};
#pragma unroll
  for (int g = 0; g < 5; ++g) {
    const uint32_t* R = (g & 1) ? RB : RA;
#pragma unroll
    for (int j = 0; j < 4; ++j) {
      x0 += x1;
      x1 = (x1 << R[j]) | (x1 >> (32u - R[j]));
      x1 ^= x0;
    }
    x0 += ks[(g + 1) % 3];
    x1 += ks[(g + 2) % 3] + (uint32_t)(g + 1);
  }
  *o0 = x0; *o1 = x1;
}

__device__ static inline uint32_t rbits32(uint32_t ka, uint32_t kb, uint32_t i) {
  uint32_t o0, o1;
  tf2x32(ka, kb, 0u, i, &o0, &o1);
  return o0 ^ o1;
}

// bijective XCD-aware block swizzle (m204 variant; works for any nwg)
__device__ static inline int xcd_swz(int orig, int nwg) {
  int q = nwg >> 3, r = nwg & 7;
  int xcd = orig & 7, idx = orig >> 3;
  return (xcd < r ? xcd * (q + 1) : r * (q + 1) + (xcd - r) * q) + idx;
}

// ---------------- block exclusive scan (all threads must call) ----------------
__device__ static inline uint32_t block_scan_excl(uint32_t v, uint32_t* lds) {
  int t = threadIdx.x;
  lds[t] = v;
  __syncthreads();
#pragma unroll
  for (int d = 1; d < THREADS; d <<= 1) {
    uint32_t add = (t >= d) ? lds[t - d] : 0u;
    __syncthreads();
    lds[t] += add;
    __syncthreads();
  }
  return lds[t] - v;
}

// ---------------- hierarchical scan helpers ----------------
__global__ void k_sums_u32(const uint32_t* __restrict__ d, int n, uint32_t* __restrict__ bsums) {
  __shared__ uint32_t lds[THREADS];
  int b = blockIdx.x, t = threadIdx.x;
  int base = b * CHUNK + t * ITEMS;
  uint32_t s = 0;
#pragma unroll
  for (int j = 0; j < ITEMS; ++j) { int i = base + j; if (i < n) s += d[i]; }
  lds[t] = s; __syncthreads();
  for (int d2 = THREADS / 2; d2 > 0; d2 >>= 1) { if (t < d2) lds[t] += lds[t + d2]; __syncthreads(); }
  if (t == 0) bsums[b] = lds[0];
}

__global__ void k_scan_single(uint32_t* __restrict__ d, int n, uint32_t* __restrict__ total_out) {
  __shared__ uint32_t lds[THREADS];
  int t = threadIdx.x;
  int K = (n + THREADS - 1) / THREADS;
  int s0 = t * K, s1 = (s0 + K < n) ? (s0 + K) : n;
  uint32_t s = 0;
  for (int j = s0; j < s1; ++j) s += d[j];
  lds[t] = s; __syncthreads();
#pragma unroll
  for (int dd = 1; dd < THREADS; dd <<= 1) {
    uint32_t a = (t >= dd) ? lds[t - dd] : 0u;
    __syncthreads();
    lds[t] += a;
    __syncthreads();
  }
  uint32_t incl = lds[t];
  if (total_out && t == THREADS - 1) *total_out = incl;
  uint32_t run = incl - s;
  for (int j = s0; j < s1; ++j) { uint32_t tmp = d[j]; d[j] = run; run += tmp; }
}

__global__ void k_excl_u32(uint32_t* __restrict__ d, int n, const uint32_t* __restrict__ bsums) {
  __shared__ uint32_t lds[THREADS];
  int b = blockIdx.x, t = threadIdx.x;
  int base = b * CHUNK + t * ITEMS;
  uint32_t v[ITEMS]; uint32_t s = 0;
#pragma unroll
  for (int j = 0; j < ITEMS; ++j) { int i = base + j; uint32_t x = (i < n) ? d[i] : 0u; v[j] = x; s += x; }
  uint32_t run = bsums[b] + block_scan_excl(s, lds);
#pragma unroll
  for (int j = 0; j < ITEMS; ++j) { int i = base + j; if (i < n) d[i] = run; run += v[j]; }
}

// ---------------- edge grouping: 2 UNSTABLE 10-bit bucket passes on ROW bits ----------------
__global__ void k_hist_row(const int* __restrict__ row, int n, int NB, uint32_t* __restrict__ hist) {
  __shared__ uint32_t h[1024];
  int b = blockIdx.x, t = threadIdx.x;
#pragma unroll
  for (int g = 0; g < 4; ++g) h[g * THREADS + t] = 0;
  __syncthreads();
  int base = b * CHUNK;
  for (int j = t; j < CHUNK; j += THREADS) {
    int i = base + j;
    if (i < n) atomicAdd(&h[(uint32_t)row[i] & 1023u], 1u);
  }
  __syncthreads();
#pragma unroll
  for (int g = 0; g < 4; ++g) {
    int d = g * THREADS + t;
    hist[(size_t)d * NB + b] = h[d];
  }
}

// pass 1 fused with packing: unstable bucket by (row & 1023) via LDS atomic ranking.
// rowsort fixes intra-row order later, so element order inside a digit is free.
__global__ __launch_bounds__(THREADS) void k_pack_scatter(
    const int* __restrict__ row, const int* __restrict__ col,
    uint64_t* __restrict__ kout, const uint32_t* __restrict__ hist, int n, int NB) {
  constexpr int DIG = 1024;
  constexpr int G = DIG / THREADS;
  __shared__ uint64_t lkeys[CHUNK];   // 32 KB; first 1 KB doubles as scan temp
  __shared__ uint32_t cur[DIG];       // counts -> cursors
  __shared__ uint32_t wofs[DIG];      // gofs - lst
  int b = xcd_swz(blockIdx.x, gridDim.x), t = threadIdx.x;
  int base = b * CHUNK;
#pragma unroll
  for (int g = 0; g < G; ++g) {
    int d = g * THREADS + t;
    cur[d] = 0;
    wofs[d] = hist[(size_t)d * NB + b];
  }
  __syncthreads();
  uint64_t mykey[ITEMS];
#pragma unroll
  for (int batch = 0; batch < ITEMS; ++batch) {
    int i = base + batch * THREADS + t;
    uint64_t key = 0ull;
    if (i < n) {
      uint32_t r = (uint32_t)row[i];
      key = ((uint64_t)r << 20) | (uint32_t)col[i];
      atomicAdd(&cur[r & 1023u], 1u);
    }
    mykey[batch] = key;
  }
  __syncthreads();
  uint32_t c[G]; uint32_t s = 0;
#pragma unroll
  for (int g = 0; g < G; ++g) { c[g] = cur[G * t + g]; s += c[g]; }
  uint32_t tp = block_scan_excl(s, (uint32_t*)lkeys);
#pragma unroll
  for (int g = 0; g < G; ++g) {
    int d = G * t + g;
    cur[d] = tp;              // cursor start = lst
    wofs[d] = wofs[d] - tp;   // gofs - lst
    tp += c[g];
  }
  __syncthreads();
#pragma unroll
  for (int batch = 0; batch < ITEMS; ++batch) {
    int i = base + batch * THREADS + t;
    if (i < n) {
      uint32_t dig = (uint32_t)(mykey[batch] >> 20) & 1023u;
      uint32_t slot = atomicAdd(&cur[dig], 1u);
      lkeys[slot] = mykey[batch];
    }
  }
  __syncthreads();
  int nloc = n - base; if (nloc > CHUNK) nloc = CHUNK;
  for (int j = t; j < nloc; j += THREADS) {
    uint64_t key = lkeys[j];
    uint32_t dig = (uint32_t)(key >> 20) & 1023u;
    kout[wofs[dig] + (uint32_t)j] = key;
  }
}

template <int DBITS>
__global__ void k_rhist64T(const uint64_t* __restrict__ keys, int n, int shift, int NB,
                           uint32_t* __restrict__ hist) {
  constexpr int DIG = 1 << DBITS;
  constexpr int G = DIG / THREADS;
  __shared__ uint32_t h[DIG];
  int b = blockIdx.x, t = threadIdx.x;
#pragma unroll
  for (int g = 0; g < G; ++g) h[g * THREADS + t] = 0;
  __syncthreads();
  int base = b * CHUNK;
  for (int j = t; j < CHUNK; j += THREADS) {
    int i = base + j;
    if (i < n) atomicAdd(&h[(uint32_t)(keys[i] >> shift) & (DIG - 1)], 1u);
  }
  __syncthreads();
#pragma unroll
  for (int g = 0; g < G; ++g) {
    int d = g * THREADS + t;
    hist[(size_t)d * NB + b] = h[d];
  }
}

// pass 2: bucket by (row >> 10). Group-stable via two-part split: a block straddles
// at most ONE pass-1 group boundary (group ~15625 >> 4096), so part = (lowdig != ref).
// Left-part elements get slots before right-part per digit -> group order preserved.
__global__ __launch_bounds__(THREADS) void k_scatter_hi(
    const uint64_t* __restrict__ kin, uint64_t* __restrict__ kout,
    const uint32_t* __restrict__ hist, int n, int NB) {
  constexpr int DIG = 1024;
  constexpr int G = DIG / THREADS;
  __shared__ uint64_t lkeys[CHUNK];   // 32 KB; first 1 KB doubles as scan temp
  __shared__ uint32_t cntL[DIG];      // left counts -> curL
  __shared__ uint32_t cntR[DIG];      // right counts -> curR
  __shared__ uint32_t wofs[DIG];      // gofs - lst
  int b = xcd_swz(blockIdx.x, gridDim.x), t = threadIdx.x;
  int base = b * CHUNK;
#pragma unroll
  for (int g = 0; g < G; ++g) {
    int d = g * THREADS + t;
    cntL[d] = 0; cntR[d] = 0;
    wofs[d] = hist[(size_t)d * NB + b];
  }
  __syncthreads();
  uint32_t ref = (uint32_t)(kin[base] >> 20) & 1023u;   // low digit of first key
  uint64_t mykey[ITEMS];
#pragma unroll
  for (int batch = 0; batch < ITEMS; ++batch) {
    int i = base + batch * THREADS + t;
    uint64_t key = 0ull;
    if (i < n) {
      key = kin[i];
      uint32_t dig = (uint32_t)(key >> 30) & 1023u;
      uint32_t low = (uint32_t)(key >> 20) & 1023u;
      atomicAdd((low == ref) ? &cntL[dig] : &cntR[dig], 1u);
    }
    mykey[batch] = key;
  }
  __syncthreads();
  uint32_t cl[G], cr[G];
  uint32_t s = 0;
#pragma unroll
  for (int g = 0; g < G; ++g) {
    cl[g] = cntL[G * t + g]; cr[g] = cntR[G * t + g];
    s += cl[g] + cr[g];
  }
  uint32_t tp = block_scan_excl(s, (uint32_t*)lkeys);
#pragma unroll
  for (int g = 0; g < G; ++g) {
    int d = G * t + g;
    cntL[d] = tp;              // curL
    cntR[d] = tp + cl[g];      // curR (after all left-part slots)
    wofs[d] = wofs[d] - tp;    // gofs - lst
    tp += cl[g] + cr[g];
  }
  __syncthreads();
#pragma unroll
  for (int batch = 0; batch < ITEMS; ++batch) {
    int i = base + batch * THREADS + t;
    if (i < n) {
      uint64_t key = mykey[batch];
      uint32_t dig = (uint32_t)(key >> 30) & 1023u;
      uint32_t low = (uint32_t)(key >> 20) & 1023u;
      uint32_t slot = atomicAdd((low == ref) ? &cntL[dig] : &cntR[dig], 1u);
      lkeys[slot] = key;
    }
  }
  __syncthreads();
  int nloc = n - base; if (nloc > CHUNK) nloc = CHUNK;
  for (int j = t; j < nloc; j += THREADS) {
    uint64_t key = lkeys[j];
    uint32_t dig = (uint32_t)(key >> 30) & 1023u;
    kout[wofs[dig] + (uint32_t)j] = key;
  }
}

// rowptr[v] = first index i with row(U[i]) >= v; rowptr[Nn] = E
__global__ void k_rowptr(const uint64_t* __restrict__ U, int E, int Nn, int* __restrict__ rowptr) {
  int i = blockIdx.x * blockDim.x + threadIdx.x;
  int st = gridDim.x * blockDim.x;
  for (; i < E; i += st) {
    int r = (int)(U[i] >> 20); if (r > Nn - 1) r = Nn - 1;
    int rp;
    if (i == 0) rp = -1;
    else { rp = (int)(U[i - 1] >> 20); if (rp > Nn - 1) rp = Nn - 1; }
    for (int v = rp + 1; v <= r; ++v) rowptr[v] = i;
    if (i == E - 1) { for (int v = r + 1; v <= Nn; ++v) rowptr[v] = E; }
  }
}

// per-row col sort in LDS: one WG = 256 consecutive rows (avg 4096 keys).
__global__ __launch_bounds__(THREADS) void k_rowsort_lds(
    const int* __restrict__ rowptr, int Nn, uint64_t* __restrict__ U) {
  __shared__ uint64_t lbuf[RS_CAP];
  int b = blockIdx.x, t = threadIdx.x;
  int r0 = b * THREADS;
  int r1 = r0 + THREADS; if (r1 > Nn) r1 = Nn;
  if (r0 >= Nn) return;
  int s = rowptr[r0], e = rowptr[r1];
  int nseg = e - s;
  int r = r0 + t;
  if (nseg <= RS_CAP) {
    for (int j = t; j < nseg; j += THREADS) lbuf[j] = U[s + j];
    __syncthreads();
    if (r < Nn) {
      int a0 = rowptr[r] - s, a1 = rowptr[r + 1] - s;
      for (int a = a0 + 1; a < a1; ++a) {
        uint64_t key = lbuf[a];
        int b2 = a - 1;
        while (b2 >= a0 && lbuf[b2] > key) { lbuf[b2 + 1] = lbuf[b2]; --b2; }
        lbuf[b2 + 1] = key;
      }
    }
    __syncthreads();
    for (int j = t; j < nseg; j += THREADS) U[s + j] = lbuf[j];
  } else {
    if (r < Nn) {
      int a0 = rowptr[r], a1 = rowptr[r + 1];
      for (int a = a0 + 1; a < a1; ++a) {
        uint64_t key = U[a];
        int b2 = a - 1;
        while (b2 >= a0 && U[b2] > key) { U[b2 + 1] = U[b2]; --b2; }
        U[b2 + 1] = key;
      }
    }
  }
}

// ---------------- permutation (1M u32 keys + payload), STABLE LSD radix ----------------
__global__ void k_genbits(uint32_t ka, uint32_t kb, int n,
                          uint32_t* __restrict__ keys, int* __restrict__ vals) {
  int i = blockIdx.x * blockDim.x + threadIdx.x;
  int st = gridDim.x * blockDim.x;
  for (; i < n; i += st) {
    keys[i] = rbits32(ka, kb, (uint32_t)i);
    if (vals) vals[i] = i;
  }
}

template <int DBITS, int IT>
__global__ void k_rhistT(const uint32_t* __restrict__ keys, int n, int shift, int NB,
                         uint32_t* __restrict__ hist) {
  constexpr int DIG = 1 << DBITS;
  constexpr int G = DIG / THREADS;
  constexpr int CH = THREADS * IT;
  __shared__ uint32_t h[DIG];
  int b = blockIdx.x, t = threadIdx.x;
#pragma unroll
  for (int g = 0; g < G; ++g) h[g * THREADS + t] = 0;
  __syncthreads();
  int base = b * CH;
  for (int j = t; j < CH; j += THREADS) {
    int i = base + j;
    if (i < n) atomicAdd(&h[(keys[i] >> shift) & (DIG - 1)], 1u);
  }
  __syncthreads();
#pragma unroll
  for (int g = 0; g < G; ++g) {
    int d = g * THREADS + t;
    hist[(size_t)d * NB + b] = h[d];
  }
}

template <int DBITS, int IT>
__global__ __launch_bounds__(THREADS) void k_rscatterT(
    const uint32_t* __restrict__ kin, const int* __restrict__ vin,
    uint32_t* __restrict__ kout, int* __restrict__ vout,
    const uint32_t* __restrict__ hist, int n, int shift, int NB) {
  constexpr int DIG = 1 << DBITS;
  constexpr int G = DIG / THREADS;
  __shared__ uint32_t offset[DIG];
  __shared__ unsigned short wcnt[4][DIG];
  unsigned short* wflat = &wcnt[0][0];
  int b = blockIdx.x, t = threadIdx.x;
#pragma unroll
  for (int g = 0; g < G; ++g) {
    int d = g * THREADS + t;
    offset[d] = hist[(size_t)d * NB + b];
  }
  __syncthreads();
  int lane = t & 63, wid = t >> 6;
  int base = b * (THREADS * IT);
  for (int batch = 0; batch < IT; ++batch) {
    int i = base + batch * THREADS + t;
    bool act = i < n;
    uint32_t key = act ? kin[i] : 0u;
    uint32_t dig = (key >> shift) & (DIG - 1);
#pragma unroll
    for (int z = 0; z < 4 * G; ++z) wflat[z * THREADS + t] = 0;
    __syncthreads();
    unsigned long long peers = __ballot(act);
#pragma unroll
    for (int bit = 0; bit < DBITS; ++bit) {
      unsigned long long m = __ballot(act && ((dig >> bit) & 1u));
      peers &= ((dig >> bit) & 1u) ? m : ~m;
    }
    uint32_t rankw = 0;
    if (act) {
      rankw = (uint32_t)__popcll(peers & ((1ull << lane) - 1ull));
      if (rankw == 0) wcnt[wid][dig] = (unsigned short)__popcll(peers);
    }
    __syncthreads();
    if (act) {
      uint32_t pre = 0;
#pragma unroll
      for (int wv = 0; wv < 4; ++wv) if (wv < wid) pre += wcnt[wv][dig];
      uint32_t dst = offset[dig] + pre + rankw;
      kout[dst] = key;
      vout[dst] = vin[i];
    }
    __syncthreads();
#pragma unroll
    for (int g = 0; g < G; ++g) {
      int d = g * THREADS + t;
      offset[d] += (uint32_t)wcnt[0][d] + wcnt[1][d] + wcnt[2][d] + wcnt[3][d];
    }
    __syncthreads();
  }
}

// ---------------- random walks ----------------
__global__ void k_walk(const int* __restrict__ start, int S,
                       const int* __restrict__ rowptr, const uint64_t* __restrict__ U,
                       uint8_t* __restrict__ hits,
                       uint32_t k0a, uint32_t k0b, uint32_t k1a, uint32_t k1b,
                       uint32_t k2a, uint32_t k2b) {
  int i = blockIdx.x * blockDim.x + threadIdx.x;
  int st = gridDim.x * blockDim.x;
  for (; i < S; i += st) {
    int cur = start[i];
    bool active = true;
    uint32_t ka[3] = {k0a, k1a, k2a};
    uint32_t kb[3] = {k0b, k1b, k2b};
#pragma unroll
    for (int s = 0; s < 3; ++s) {
      int rp = rowptr[cur];
      int d = rowptr[cur + 1] - rp;
      bool act = active && (d > 0);
      if (act) hits[cur] = 1;
      uint32_t bits = rbits32(ka[s], kb[s], (uint32_t)i);
      float u = __uint_as_float((bits >> 9) | 0x3f800000u) - 1.0f;  // jax uniform [0,1)
      int off = (int)floorf(u * (float)d);
      int dm1 = d - 1; if (dm1 < 0) dm1 = 0;
      if (off > dm1) off = dm1;
      if (act) cur = (int)(U[rp + off] & COLMASK);
      active = act;
    }
  }
}

// ---------------- outputs (masked edges only exist at i < Nn) ----------------
__global__ void k_mask_copy(const uint8_t* __restrict__ hits, const uint64_t* __restrict__ U,
                            int Nn, uint32_t* __restrict__ bsums, uint64_t* __restrict__ hstage) {
  __shared__ uint32_t lds[THREADS];
  int b = blockIdx.x, t = threadIdx.x;
  int base = b * CHUNK + t * ITEMS;
  uint32_t s = 0;
#pragma unroll
  for (int j = 0; j < ITEMS; ++j) {
    int i = base + j;
    if (i < Nn) { s += (uint32_t)(!hits[i]); hstage[i] = U[i]; }
  }
  lds[t] = s; __syncthreads();
  for (int d2 = THREADS / 2; d2 > 0; d2 >>= 1) { if (t < d2) lds[t] += lds[t + d2]; __syncthreads(); }
  if (t == 0) bsums[b] = lds[0];
}

__global__ void k_out_tail(const uint64_t* __restrict__ U, int E, int Nn,
                           const uint32_t* __restrict__ keephead,
                           int* __restrict__ A, int* __restrict__ B, int* __restrict__ M) {
  int nm = Nn - (int)*keephead;
  int i = Nn + blockIdx.x * blockDim.x + threadIdx.x;
  int st = gridDim.x * blockDim.x;
  for (; i < E; i += st) {
    uint64_t key = U[i];
    A[i - nm] = (int)(key >> 20);
    B[i - nm] = (int)(key & COLMASK);
    M[i] = 1;
  }
}

__global__ void k_out_headCD(const uint64_t* __restrict__ hstage, const uint8_t* __restrict__ hits,
                             int Nn, const uint32_t* __restrict__ bsums,
                             int* __restrict__ A, int* __restrict__ B,
                             int* __restrict__ C, int* __restrict__ D, int* __restrict__ M) {
  __shared__ uint32_t lds[THREADS];
  int b = blockIdx.x, t = threadIdx.x;
  int base = b * CHUNK + t * ITEMS;
  uint32_t keep[ITEMS]; uint32_t s = 0;
#pragma unroll
  for (int j = 0; j < ITEMS; ++j) {
    int i = base + j;
    uint32_t k = (i < Nn) ? (uint32_t)(!hits[i]) : 0u;
    keep[j] = k; s += k;
  }
  uint32_t kr = bsums[b] + block_scan_excl(s, lds);
#pragma unroll
  for (int j = 0; j < ITEMS; ++j) {
    int i = base + j;
    if (i < Nn) {
      uint64_t key = hstage[i];
      if (keep[j]) { A[kr] = (int)(key >> 20); B[kr] = (int)(key & COLMASK); M[i] = 1; ++kr; }
      else { uint32_t mr = (uint32_t)i - kr; C[mr] = (int)(key >> 20); D[mr] = (int)(key & COLMASK); M[i] = 0; }
    }
  }
}

__global__ void k_cdfill(int E, int Nn, const uint32_t* __restrict__ keephead,
                         int* __restrict__ A, int* __restrict__ B,
                         int* __restrict__ C, int* __restrict__ D) {
  int nm = Nn - (int)*keephead;
  int j = blockIdx.x * blockDim.x + threadIdx.x;
  int st = gridDim.x * blockDim.x;
  for (; j < E; j += st) {
    if (j >= nm) { C[j] = -1; D[j] = -1; }
    if (j >= E - nm) { A[j] = -1; B[j] = -1; }
  }
}

// ---------------- launcher ----------------
extern "C" void kernel_launch(void* const* d_in, const int* in_sizes, int n_in,
                              void* d_out, int out_size, void* d_ws, size_t ws_size,
                              hipStream_t stream) {
  const int E = in_sizes[0] / 2;
  const int Nn = 1000000;   // num_nodes (fixed problem)
  const int S = 700000;     // round(0.7*N) * WALKS_PER_NODE
  const int NB_N = (Nn + CHUNK - 1) / CHUNK;      // 245
  const int NB_E = (E + CHUNK - 1) / CHUNK;       // 3907
  const int NB_R = (Nn + THREADS - 1) / THREADS;  // 3907 rowsort WGs
  const int PIT = 4;                              // perm ITEMS
  const int NB_P = (Nn + THREADS * PIT - 1) / (THREADS * PIT);  // 977

  const int* row = (const int*)d_in[0];
  const int* col = row + (size_t)E;

  int* out = (int*)d_out;
  int* A = out;                      // final: remaining rows
  int* B = out + (size_t)E;          // final: remaining cols
  int* C = out + (size_t)2 * E;      // final: masked rows
  int* D = out + (size_t)3 * E;      // final: masked cols
  int* M = out + (size_t)4 * E;      // final: edge_mask; staging: perm bufs + hists
  uint64_t* U0 = (uint64_t*)out;                    // spans A+B (128MB)
  uint64_t* U1 = (uint64_t*)(out + (size_t)2 * E);  // spans C+D (128MB)

  // workspace carve (same proven budget)
  char* w = (char*)d_ws;
  uint64_t* hstage = (uint64_t*)w;            // 8,000,000 B (output phase only)
  int* rowptr = (int*)w;                      // 4,000,004 B (aliases hstage; dead after walk)
  w += (size_t)Nn * 8;
  uint8_t* hits = (uint8_t*)w; w += Nn;       // 1,000,000 B
  w = (char*)(((uintptr_t)w + 255) & ~(uintptr_t)255);
  uint32_t* bsums = (uint32_t*)w; w += (size_t)4096 * 4;
  uint32_t* scal = (uint32_t*)w;  w += 64;
  if ((size_t)(w - (char*)d_ws) > ws_size) return;  // insufficient scratch: fail visibly

  // staging inside M region (64 MB): perm bufs [0,16MB), hists at [16MB,...)
  uint32_t* pkA = (uint32_t*)M;
  int*      pvA = M + (size_t)Nn;
  uint32_t* pkB = (uint32_t*)(M + (size_t)2 * Nn);
  int*      pvB = M + (size_t)3 * Nn;
  uint32_t* ehist = (uint32_t*)(M + (size_t)4 * Nn);  // up to 16,003,072 B

  // ---- host-side key derivation (JAX threefry, partitionable split = fold_in) ----
  struct KK { uint32_t a, b; };
  auto fold = [](KK k, uint32_t j) { KK r; tf2x32(k.a, k.b, 0u, j, &r.a, &r.b); return r; };
  KK base{0u, 42u};
  KK kperm = fold(base, 0u);
  KK kwalk = fold(base, 1u);
  KK keyA  = fold(kperm, 0u);
  KK sub1  = fold(kperm, 1u);
  KK sub2  = fold(keyA, 1u);
  KK wk0 = fold(kwalk, 0u), wk1 = fold(kwalk, 1u), wk2 = fold(kwalk, 2u);

  auto scan_u32 = [&](uint32_t* d, int n) {
    int SB = (n + CHUNK - 1) / CHUNK;
    k_sums_u32<<<SB, THREADS, 0, stream>>>(d, n, bsums);
    k_scan_single<<<1, THREADS, 0, stream>>>(bsums, SB, (uint32_t*)nullptr);
    k_excl_u32<<<SB, THREADS, 0, stream>>>(d, n, bsums);
  };

  hipMemsetAsync(hits, 0, (size_t)Nn, stream);

  // ---- 1) edge grouping by row: 2 unstable 10-bit bucket passes ----
  k_hist_row<<<NB_E, THREADS, 0, stream>>>(row, E, NB_E, ehist);
  scan_u32(ehist, 1024 * NB_E);
  k_pack_scatter<<<NB_E, THREADS, 0, stream>>>(row, col, U0, ehist, E, NB_E);
  k_rhist64T<10><<<NB_E, THREADS, 0, stream>>>(U0, E, 30, NB_E, ehist);
  scan_u32(ehist, 1024 * NB_E);
  k_scatter_hi<<<NB_E, THREADS, 0, stream>>>(U0, U1, ehist, E, NB_E);

  // ---- 2) rowptr, then per-row col sort in LDS (lex order complete after this) ----
  k_rowptr<<<4096, THREADS, 0, stream>>>(U1, E, Nn, rowptr);
  k_rowsort_lds<<<NB_R, THREADS, 0, stream>>>(rowptr, Nn, U1);

  // ---- 3) jax.random.permutation(kperm, N): 2 rounds of stable sort by random u32 ----
  auto radix3 = [&](uint32_t* kA, int* vA, uint32_t* kB, int* vB) {
    uint32_t* ki = kA; int* vi = vA; uint32_t* ko = kB; int* vo = vB;
    for (int p = 0; p < 3; ++p) {
      int shift = p * 11;
      k_rhistT<11, PIT><<<NB_P, THREADS, 0, stream>>>(ki, Nn, shift, NB_P, ehist);
      scan_u32(ehist, 2048 * NB_P);
      k_rscatterT<11, PIT><<<NB_P, THREADS, 0, stream>>>(ki, vi, ko, vo, ehist, Nn, shift, NB_P);
      uint32_t* tk = ki; ki = ko; ko = tk;
      int* tv = vi; vi = vo; vo = tv;
    }
  };
  k_genbits<<<2048, THREADS, 0, stream>>>(sub1.a, sub1.b, Nn, pkB, pvB);
  radix3(pkB, pvB, pkA, pvA);  // odd #passes: ends in (pkA, pvA)
  k_genbits<<<2048, THREADS, 0, stream>>>(sub2.a, sub2.b, Nn, pkB, (int*)nullptr);
  radix3(pkB, pvA, pkA, pvB);  // keys fresh in pkB, payload = perm in pvA; ends in (pkA, pvB)
  int* permv = pvB;

  // ---- 4) random walks: mark hit nodes ----
  k_walk<<<(S + THREADS - 1) / THREADS, THREADS, 0, stream>>>(
      permv, S, rowptr, U1, hits, wk0.a, wk0.b, wk1.a, wk1.b, wk2.a, wk2.b);

  // ---- 5) outputs: copy head + keep-scan, tail shift, head compaction, -1 fills ----
  k_mask_copy<<<NB_N, THREADS, 0, stream>>>(hits, U1, Nn, bsums, hstage);
  k_scan_single<<<1, THREADS, 0, stream>>>(bsums, NB_N, &scal[0]);   // scal[0] = keeps among i<Nn
  k_out_tail<<<4096, THREADS, 0, stream>>>(U1, E, Nn, &scal[0], A, B, M);
  k_out_headCD<<<NB_N, THREADS, 0, stream>>>(hstage, hits, Nn, bsums, A, B, C, D, M);
  k_cdfill<<<4096, THREADS, 0, stream>>>(E, Nn, &scal[0], A, B, C, D);
}